// Round 8
// baseline (51.916 us; speedup 1.0000x reference)
//
#include <hip/hip_runtime.h>
#include <math.h>

#define NROWS 4096
#define D 128
#define SPC 8
#define KRET 7
#define MARGIN 0.2f
#define NTILE 32              // 4096/128 column tiles
#define CPT 14                // candidates per (row, tile): 2 quadrants x top-7
#define CPR (NTILE * CPT)     // 448 candidates per row

typedef unsigned long long u64;
typedef unsigned int u32;
typedef __attribute__((ext_vector_type(8))) short short8;   // 8 bf16 (4 VGPRs)
typedef __attribute__((ext_vector_type(4))) float f32x4;    // MFMA accumulator

__device__ __forceinline__ u64 minu(u64 a, u64 b) { return a < b ? a : b; }
__device__ __forceinline__ u32 minu32(u32 a, u32 b) { return a < b ? a : b; }
__device__ __forceinline__ u32 maxu32(u32 a, u32 b) { return a > b ? a : b; }

// bf16 round-to-nearest-even
__device__ __forceinline__ ushort f2bf_rne(float x) {
    unsigned u = __float_as_uint(x);
    unsigned r = (u + 0x7fffu + ((u >> 16) & 1u)) >> 16;
    return (ushort)r;
}

// ws layout (floats):
//   [0..1]               (fallback accums only)
//   [4096 .. 8191]       diag
//   [8192 .. 40959]      posd (4096 x 8 f32, stores clamped d^2)
//   [40960 .. 106495]    embH  (4096x128 bf16)
//   [106496 .. 172031]   emb1H (4096x128 bf16)
//   [172032 .. 2007039]  cand (u32, 4096 x 448)
//   [2007040 ..]         rowls (4096), rowcnt (4096)

// ---- prep: bf16 round of both matrices + exact f32 Gram diagonal ----
__global__ __launch_bounds__(256) void prep_kernel(const float* __restrict__ emb,
                                                   const float* __restrict__ emb1,
                                                   ushort* __restrict__ embH,
                                                   ushort* __restrict__ emb1H,
                                                   float* __restrict__ diag) {
    const int lane = threadIdx.x & 63;
    const int row = blockIdx.x * 4 + (threadIdx.x >> 6);
    const size_t base = (size_t)row * D + 2 * lane;
    const float2 a = *(const float2*)(emb + base);
    const float2 b = *(const float2*)(emb1 + base);

    *(ushort2*)(embH + base)  = make_ushort2(f2bf_rne(a.x), f2bf_rne(a.y));
    *(ushort2*)(emb1H + base) = make_ushort2(f2bf_rne(b.x), f2bf_rne(b.y));

    float s = a.x * b.x + a.y * b.y;
#pragma unroll
    for (int off = 1; off < 64; off <<= 1) s += __shfl_xor(s, off, 64);
    if (lane == 0) diag[row] = s;
}

// ---- dist: barrier-free 64x64 quadrant waves, frags from L2-hot global ----
// Block = 128x128 tile as 4 INDEPENDENT 64x64 quadrants (one per wave).
// LDS: per-wave score buf [64][68] u16 (pad-68: 2-way-free writes & staggered reads)
//      + shared diag/labels (one barrier at start, then free-running).
__global__ __launch_bounds__(256, 4) void dist_mfma(const ushort* __restrict__ embH,
                                                    const ushort* __restrict__ emb1H,
                                                    const int* __restrict__ labels,
                                                    const int* __restrict__ labels1,
                                                    const float* __restrict__ diag,
                                                    float* __restrict__ posd, u32* __restrict__ cand) {
    __shared__ ushort distq[4][64][68];   // 34816 B
    __shared__ float sdA[128], sdB[128];
    __shared__ int sLi[128], sLj[128];

    const int t = threadIdx.x;
    const int i0 = blockIdx.y * 128, j0 = blockIdx.x * 128;
    const int w = t >> 6, l = t & 63;

    if (t < 128) { sdA[t] = diag[i0 + t]; sLi[t] = labels1[i0 + t]; }
    else         { sdB[t - 128] = diag[j0 + t - 128]; sLj[t - 128] = labels[j0 + t - 128]; }
    __syncthreads();          // the ONLY block barrier

    const int R = (w >> 1) * 64, C = (w & 1) * 64;
    const int lr = l & 15, lg = l >> 4;

    // wave-uniform positive-overlap gate (generic: label-range intersection)
    int mnA = sLi[R + l], mxA = mnA;
    int mnB = sLj[C + l], mxB = mnB;
#pragma unroll
    for (int off = 1; off < 64; off <<= 1) {
        mnA = min(mnA, __shfl_xor(mnA, off, 64));
        mxA = max(mxA, __shfl_xor(mxA, off, 64));
        mnB = min(mnB, __shfl_xor(mnB, off, 64));
        mxB = max(mxB, __shfl_xor(mxB, off, 64));
    }
    const bool hasPos = !(mxA < mnB || mxB < mnA);

    f32x4 acc[4][4];
#pragma unroll
    for (int m = 0; m < 4; ++m)
#pragma unroll
        for (int n = 0; n < 4; ++n) acc[m][n] = (f32x4){0.f, 0.f, 0.f, 0.f};

    // K-loop: fragments straight from global (embH/emb1H are 1 MB each, L2-resident)
    const ushort* Ab = embH  + (size_t)(i0 + R + lr) * D;
    const ushort* Bb = emb1H + (size_t)(j0 + C + lr) * D;
#pragma unroll 1
    for (int ks = 0; ks < 4; ++ks) {
        const int ko = ks * 32 + lg * 8;
        short8 ah[4], bh[4];
#pragma unroll
        for (int m = 0; m < 4; ++m) {
            ah[m] = *(const short8*)(Ab + (size_t)m * 16 * D + ko);
            bh[m] = *(const short8*)(Bb + (size_t)m * 16 * D + ko);
        }
#pragma unroll
        for (int m = 0; m < 4; ++m)
#pragma unroll
            for (int n = 0; n < 4; ++n)
                acc[m][n] = __builtin_amdgcn_mfma_f32_16x16x32_bf16(ah[m], bh[n], acc[m][n], 0, 0, 0);
    }

    // epilogue: clamped d^2 -> bf16 u16 scores in this wave's own quadrant buffer.
    // C/D layout (m89-verified): col = lane&15, row = (lane>>4)*4 + reg
    float sdA_r[16], sdB_c[4];
#pragma unroll
    for (int m = 0; m < 4; ++m)
#pragma unroll
        for (int r = 0; r < 4; ++r) sdA_r[m * 4 + r] = sdA[R + 16 * m + 4 * lg + r];
#pragma unroll
    for (int n = 0; n < 4; ++n) sdB_c[n] = sdB[C + 16 * n + lr];

    ushort (*dq)[68] = distq[w];
    if (!hasPos) {
#pragma unroll
        for (int m = 0; m < 4; ++m)
#pragma unroll
            for (int n = 0; n < 4; ++n)
#pragma unroll
                for (int r = 0; r < 4; ++r) {
                    const int row = 16 * m + 4 * lg + r;
                    const int col = 16 * n + lr;
                    const float d2c = fmaxf(sdA_r[m * 4 + r] + sdB_c[n] - 2.f * acc[m][n][r], 1e-4f);
                    dq[row][col] = f2bf_rne(d2c);
                }
    } else {
        int sLi_r[16], sLj_c[4];
#pragma unroll
        for (int m = 0; m < 4; ++m)
#pragma unroll
            for (int r = 0; r < 4; ++r) sLi_r[m * 4 + r] = sLi[R + 16 * m + 4 * lg + r];
#pragma unroll
        for (int n = 0; n < 4; ++n) sLj_c[n] = sLj[C + 16 * n + lr];
#pragma unroll
        for (int m = 0; m < 4; ++m)
#pragma unroll
            for (int n = 0; n < 4; ++n)
#pragma unroll
                for (int r = 0; r < 4; ++r) {
                    const int row = 16 * m + 4 * lg + r;
                    const int col = 16 * n + lr;
                    const int gi = i0 + R + row, gj = j0 + C + col;
                    const float d2c = fmaxf(sdA_r[m * 4 + r] + sdB_c[n] - 2.f * acc[m][n][r], 1e-4f);
                    const bool pos = (sLj_c[n] == sLi_r[m * 4 + r]) && (gi != gj);
                    if (pos) posd[(size_t)gi * SPC + (gj & (SPC - 1))] = d2c;
                    dq[row][col] = pos ? (ushort)0xFFFFu : f2bf_rne(d2c);
                }
    }

    // wave-local sync only: this wave wrote exactly the quadrant it scans
    asm volatile("s_waitcnt lgkmcnt(0)" ::: "memory");
    __builtin_amdgcn_sched_barrier(0);

    // selection: 1 thread per row, b32 paired reads (2 cols), dual-insert sorted-7.
    // u32 pack (score16|col12): exact (score, col) lexicographic order = reference tie-break.
    {
        u32 s[KRET];
#pragma unroll
        for (int k = 0; k < KRET; ++k) s[k] = 0xFFFFFFFFu;
        const ushort* dr = &dq[l][0];
        const u32 cbase = (u32)(j0 + C);
#pragma unroll 4
        for (int c = 0; c < 32; ++c) {
            const int cc = (2 * (c + l)) & 63;        // even stagger: aligned b32, 2-way banks
            const u32 rcc = *(const u32*)(dr + cc);
            const u32 p0 = (rcc << 16) | (cbase + cc);
            const u32 p1 = (rcc & 0xFFFF0000u) | (cbase + cc + 1);
            const u32 q0 = minu32(p0, p1);
            const u32 q1 = maxu32(p0, p1);
            // merge sorted pair (q0<=q1) into sorted-7, keep 7 (descending k: uses old s)
            s[6] = minu32(s[6], minu32(maxu32(s[5], q0), maxu32(s[4], q1)));
            s[5] = minu32(s[5], minu32(maxu32(s[4], q0), maxu32(s[3], q1)));
            s[4] = minu32(s[4], minu32(maxu32(s[3], q0), maxu32(s[2], q1)));
            s[3] = minu32(s[3], minu32(maxu32(s[2], q0), maxu32(s[1], q1)));
            s[2] = minu32(s[2], minu32(maxu32(s[1], q0), maxu32(s[0], q1)));
            s[1] = minu32(s[1], minu32(maxu32(s[0], q0), q1));
            s[0] = minu32(s[0], q0);
        }
        u32* cw = cand + (size_t)(i0 + R + l) * CPR + (j0 >> 7) * CPT + (C >> 6) * KRET;
#pragma unroll
        for (int k = 0; k < KRET; ++k) cw[k] = s[k];
    }
}

// ---- merge 448 u32 candidates/row -> global top-7, validity, loss. Wave per row. ----
__global__ __launch_bounds__(256) void merge_kernel(const float* __restrict__ emb,
                                                    const float* __restrict__ posd,
                                                    const u32* __restrict__ cand,
                                                    float* __restrict__ rowls,
                                                    float* __restrict__ rowcnt) {
    const int lane = threadIdx.x & 63;
    const int i = blockIdx.x * 4 + (threadIdx.x >> 6);
    const u32* cr = cand + (size_t)i * CPR;
    u32 e[7];
#pragma unroll
    for (int q = 0; q < 7; ++q) e[q] = cr[q * 64 + lane];

    u32 w[KRET];
#pragma unroll
    for (int r = 0; r < KRET; ++r) {
        u32 m = e[0];
#pragma unroll
        for (int q = 1; q < 7; ++q) m = minu32(m, e[q]);
#pragma unroll
        for (int off = 1; off < 64; off <<= 1) m = minu32(m, (u32)__shfl_xor((int)m, off, 64));
        w[r] = m;
#pragma unroll
        for (int q = 0; q < 7; ++q) e[q] = (e[q] == m) ? 0xFFFFFFFFu : e[q];
    }

    // sort winners by column index: rotate to (col12 << 20 | score16 << 4), Batcher-8
    u32 s[8];
#pragma unroll
    for (int r = 0; r < KRET; ++r) s[r] = (w[r] << 20) | (w[r] >> 12);
    s[7] = 0xFFFFFFFFu;
#define CE(x, y) { u32 lo = minu32(s[x], s[y]); u32 hi = maxu32(s[x], s[y]); s[x] = lo; s[y] = hi; }
    CE(0,1) CE(2,3) CE(4,5) CE(6,7)
    CE(0,2) CE(1,3) CE(4,6) CE(5,7)
    CE(1,2) CE(5,6)
    CE(0,4) CE(1,5) CE(2,6) CE(3,7)
    CE(2,4) CE(3,5)
    CE(1,2) CE(3,4) CE(5,6)
#undef CE

    const int ig = i & (SPC - 1);
    float ls = 0.f, cnt = 0.f;
    bool any = false;
    bool v[KRET];
    int nidx[KRET];
#pragma unroll
    for (int k = 0; k < KRET; ++k) {
        nidx[k] = (int)(s[k] >> 20);
        const float d2n = __uint_as_float(((s[k] >> 4) & 0xFFFF0u) << 12);  // score16 << 16
        const float dneg = sqrtf(d2n);
        const int m = k + (k >= ig ? 1 : 0);
        const float dp = sqrtf(posd[(size_t)i * SPC + m]);
        v[k] = dp < dneg + MARGIN;       // wave-uniform
        any = any || v[k];
    }

    if (any) {
        const float a0 = emb[(size_t)i * D + lane];
        const float a1 = emb[(size_t)i * D + 64 + lane];
#pragma unroll
        for (int k = 0; k < KRET; ++k) {
            if (v[k]) {
                const int m = k + (k >= ig ? 1 : 0);
                const int tp = (i & ~(SPC - 1)) + m;
                const int tn = nidx[k];
                float d0 = emb[(size_t)tp * D + lane] - a0;
                float d1 = emb[(size_t)tp * D + 64 + lane] - a1;
                float sp = d0 * d0 + d1 * d1;
                float g0 = emb[(size_t)tn * D + lane] - a0;
                float g1 = emb[(size_t)tn * D + 64 + lane] - a1;
                float sn = g0 * g0 + g1 * g1;
#pragma unroll
                for (int off = 1; off < 64; off <<= 1) {
                    sp += __shfl_xor(sp, off, 64);
                    sn += __shfl_xor(sn, off, 64);
                }
                ls += (sqrtf(sp + 1e-8f) + MARGIN) + fmaxf(MARGIN - sqrtf(sn + 1e-8f), 0.f);
                cnt += 1.f;
            }
        }
    }
    if (lane == 0) {           // always write: poison-safe, deterministic
        rowls[i] = ls;
        rowcnt[i] = cnt;
    }
}

// ---- deterministic single-block reduction over 4096 per-row partials ----
__global__ __launch_bounds__(256) void finalize_kernel(const float* __restrict__ rowls,
                                                       const float* __restrict__ rowcnt,
                                                       float* __restrict__ out) {
    const int t = threadIdx.x;
    __shared__ float sls[4], scnt[4];
    float ls = 0.f, cnt = 0.f;
#pragma unroll
    for (int q = 0; q < NROWS / 256; ++q) {
        ls += rowls[q * 256 + t];
        cnt += rowcnt[q * 256 + t];
    }
#pragma unroll
    for (int off = 1; off < 64; off <<= 1) {
        ls += __shfl_xor(ls, off, 64);
        cnt += __shfl_xor(cnt, off, 64);
    }
    if ((t & 63) == 0) { sls[t >> 6] = ls; scnt[t >> 6] = cnt; }
    __syncthreads();
    if (t == 0) {
        float L = sls[0] + sls[1] + sls[2] + sls[3];
        float C = scnt[0] + scnt[1] + scnt[2] + scnt[3];
        out[0] = C > 0.f ? L / C : L;
    }
}

// ---------------- Fallback path (round-1, only if ws too small) ----------------
__global__ __launch_bounds__(256) void diag_kernel(const float* __restrict__ emb,
                                                   const float* __restrict__ emb1,
                                                   float* __restrict__ diag) {
    int wave = threadIdx.x >> 6;
    int lane = threadIdx.x & 63;
    int row = blockIdx.x * 4 + wave;
    const float* a = emb + (size_t)row * D;
    const float* b = emb1 + (size_t)row * D;
    float s = a[lane] * b[lane] + a[lane + 64] * b[lane + 64];
    for (int off = 32; off > 0; off >>= 1) s += __shfl_down(s, off, 64);
    if (lane == 0) diag[row] = s;
}

__global__ __launch_bounds__(256) void main_kernel(const float* __restrict__ emb,
                                                   const float* __restrict__ emb1,
                                                   const int* __restrict__ labels,
                                                   const int* __restrict__ labels1,
                                                   const float* __restrict__ diag,
                                                   float* __restrict__ ws_acc) {
    const int i = blockIdx.x;
    const int tid = threadIdx.x;
    __shared__ float s_anchor[D];
    __shared__ float s_posd[SPC];
    __shared__ u64 s_red[4];
    __shared__ u64 s_win;
    __shared__ int s_negidx[KRET];
    __shared__ float s_negd[KRET];
    __shared__ float s_dreal[2 * KRET];

    if (tid < D) s_anchor[tid] = emb[(size_t)i * D + tid];
    __syncthreads();
    const float diag_i = diag[i];
    const int li = labels1[i];
    float score[16];
#pragma unroll
    for (int it = 0; it < 16; ++it) {
        int j = it * 256 + tid;
        const float4* r = (const float4*)(emb1 + (size_t)j * D);
        float acc = 0.f;
#pragma unroll
        for (int q = 0; q < D / 4; ++q) {
            float4 vv = r[q];
            acc = fmaf(vv.x, s_anchor[4 * q + 0], acc);
            acc = fmaf(vv.y, s_anchor[4 * q + 1], acc);
            acc = fmaf(vv.z, s_anchor[4 * q + 2], acc);
            acc = fmaf(vv.w, s_anchor[4 * q + 3], acc);
        }
        float d2 = diag_i + diag[j] - 2.f * acc;
        float dist = sqrtf(fmaxf(d2, 1e-4f));
        bool is_pos = (labels[j] == li) && (j != i);
        if (is_pos) s_posd[j & (SPC - 1)] = dist;
        score[it] = dist + (is_pos ? 1e6f : 0.f);
    }
    __syncthreads();
    for (int r = 0; r < KRET; ++r) {
        u64 best = ~0ull;
#pragma unroll
        for (int it = 0; it < 16; ++it) {
            u64 p = ((u64)__float_as_uint(score[it]) << 32) | (unsigned)(it * 256 + tid);
            best = best < p ? best : p;
        }
        for (int off = 32; off > 0; off >>= 1) {
            u64 o = __shfl_down(best, off, 64);
            best = best < o ? best : o;
        }
        if ((tid & 63) == 0) s_red[tid >> 6] = best;
        __syncthreads();
        if (tid == 0) {
            u64 w2 = s_red[0];
            w2 = w2 < s_red[1] ? w2 : s_red[1];
            w2 = w2 < s_red[2] ? w2 : s_red[2];
            w2 = w2 < s_red[3] ? w2 : s_red[3];
            s_win = w2;
        }
        __syncthreads();
        u64 w2 = s_win;
        int cj = (int)(w2 & 0xffffffffu);
        if (tid == (cj & 255)) score[cj >> 8] = 1e30f;
        if (tid == 0) { s_negidx[r] = cj; s_negd[r] = __uint_as_float((unsigned)(w2 >> 32)); }
        __syncthreads();
    }
    if (tid == 0) {
        for (int a = 1; a < KRET; ++a) {
            int ix = s_negidx[a]; float dv = s_negd[a];
            int b = a - 1;
            while (b >= 0 && s_negidx[b] > ix) {
                s_negidx[b + 1] = s_negidx[b]; s_negd[b + 1] = s_negd[b]; --b;
            }
            s_negidx[b + 1] = ix; s_negd[b + 1] = dv;
        }
    }
    __syncthreads();
    {
        int wave = tid >> 6, lane = tid & 63;
        int gb = i & ~(SPC - 1);
        for (int p = wave; p < 2 * KRET; p += 4) {
            int tgt;
            if (p < KRET) {
                int k = p;
                int m = k + (k >= (i & (SPC - 1)) ? 1 : 0);
                tgt = gb + m;
            } else tgt = s_negidx[p - KRET];
            float d0 = emb[(size_t)tgt * D + lane] - s_anchor[lane];
            float d1 = emb[(size_t)tgt * D + 64 + lane] - s_anchor[64 + lane];
            float s = d0 * d0 + d1 * d1;
            for (int off = 32; off > 0; off >>= 1) s += __shfl_down(s, off, 64);
            if (lane == 0) s_dreal[p] = sqrtf(s + 1e-8f);
        }
    }
    __syncthreads();
    if (tid == 0) {
        float ls = 0.f, cnt = 0.f;
        for (int k = 0; k < KRET; ++k) {
            int m = k + (k >= (i & (SPC - 1)) ? 1 : 0);
            if (s_posd[m] < s_negd[k] + MARGIN) {
                ls += (s_dreal[k] + MARGIN) + fmaxf(MARGIN - s_dreal[KRET + k], 0.f);
                cnt += 1.f;
            }
        }
        if (ls != 0.f) atomicAdd(&ws_acc[0], ls);
        if (cnt != 0.f) atomicAdd(&ws_acc[1], cnt);
    }
}

__global__ void finalize_ws(const float* __restrict__ ws_acc, float* __restrict__ out) {
    float ls = ws_acc[0], cnt = ws_acc[1];
    out[0] = cnt > 0.f ? ls / cnt : ls;
}

extern "C" void kernel_launch(void* const* d_in, const int* in_sizes, int n_in,
                              void* d_out, int out_size, void* d_ws, size_t ws_size,
                              hipStream_t stream) {
    const float* emb     = (const float*)d_in[0];
    const int*   labels  = (const int*)d_in[1];
    const float* emb1    = (const float*)d_in[2];
    const int*   labels1 = (const int*)d_in[3];
    float* ws = (float*)d_ws;

    const size_t need = (size_t)2015232 * sizeof(float);
    if (ws_size >= need) {
        float*  diag   = ws + 4096;
        float*  posd   = ws + 8192;
        ushort* embH   = (ushort*)(ws + 40960);
        ushort* emb1H  = (ushort*)(ws + 106496);
        u32*    cand   = (u32*)(ws + 172032);
        float*  rowls  = ws + 2007040;
        float*  rowcnt = ws + 2011136;

        prep_kernel<<<NROWS / 4, 256, 0, stream>>>(emb, emb1, embH, emb1H, diag);
        dim3 grid(NROWS / 128, NROWS / 128);
        dist_mfma<<<grid, 256, 0, stream>>>(embH, emb1H, labels, labels1, diag, posd, cand);
        merge_kernel<<<NROWS / 4, 256, 0, stream>>>(emb, posd, cand, rowls, rowcnt);
        finalize_kernel<<<1, 256, 0, stream>>>(rowls, rowcnt, (float*)d_out);
    } else {
        hipMemsetAsync(d_ws, 0, 2 * sizeof(float), stream);
        float* diag = ws + 2;
        diag_kernel<<<NROWS / 4, 256, 0, stream>>>(emb, emb1, diag);
        main_kernel<<<NROWS, 256, 0, stream>>>(emb, emb1, labels, labels1, diag, ws);
        finalize_ws<<<1, 1, 0, stream>>>(ws, (float*)d_out);
    }
}